// Round 4
// baseline (425.604 us; speedup 1.0000x reference)
//
#include <hip/hip_runtime.h>
#include <math.h>

#define BATCH 2
#define NHEAD 16
#define SLEN  2048
#define DH    64
#define WAVES 4            // waves per block
#define QW    16           // q rows per wave
#define QB    (WAVES*QW)   // 64 q rows per block
#define KB    32           // keys per k-step
#define PSTRIDE 36         // dwords per P row in LDS (32 + 4 pad)

typedef __attribute__((ext_vector_type(8))) short bf16x8;
typedef __attribute__((ext_vector_type(4))) float f32x4;

__device__ __forceinline__ unsigned rotl32(unsigned x, unsigned d) {
    return (x << d) | (x >> (32u - d));
}

// jax.random.bernoulli(jax.random.key(42)) bits, jax_threefry_partitionable=True:
// counter = (0, i); bits = out0 ^ out1 of threefry2x32 with key (0, 42).
__device__ __forceinline__ unsigned threefry_bits(unsigned i) {
    const unsigned k0 = 0u, k1 = 42u;
    const unsigned ks[3] = { k0, k1, k0 ^ k1 ^ 0x1BD11BDAu };
    unsigned x0 = 0u + ks[0];
    unsigned x1 = i  + ks[1];
    const unsigned rot[2][4] = { {13u,15u,26u,6u}, {17u,29u,16u,24u} };
#pragma unroll
    for (int g = 0; g < 5; ++g) {
#pragma unroll
        for (int r = 0; r < 4; ++r) {
            x0 += x1;
            x1 = rotl32(x1, rot[g & 1][r]);
            x1 ^= x0;
        }
        x0 += ks[(g + 1) % 3];
        x1 += ks[(g + 2) % 3] + (unsigned)(g + 1);
    }
    return x0 ^ x1;
}

// keep iff uniform(bits) < 0.9f  ⟺  (bits>>9) < 7549747  ⟺  bits < 7549747<<9
__device__ __forceinline__ int keep(unsigned flat) {
    return threefry_bits(flat) < 3865470464u;
}

// fp32 -> bf16 round-to-nearest-even
__device__ __forceinline__ short f2bf(float f) {
    unsigned u = __float_as_uint(f);
    u = (u + 0x7fffu + ((u >> 16) & 1u)) >> 16;
    return (short)u;
}

__global__ __launch_bounds__(256)
void attn_mfma_kernel(const float* __restrict__ Q,
                      const float* __restrict__ KV,
                      float* __restrict__ O) {
    // K tile, bf16 [KB][64], row = 8 16B-chunks, chunk XOR-swizzled by row&7
    __shared__ bf16x8 s_k[KB * 8];                // 4 KB
    // V^T tile, bf16 [DH][row stride 5 chunks = 80B], first 4 chunks = 32 k's
    __shared__ bf16x8 s_vt[DH * 5];               // 5 KB
    // per-wave P relayout buffer (fp32)
    __shared__ float s_p[WAVES][QW][PSTRIDE];     // 9 KB

    const int tid  = threadIdx.x;
    const int wave = tid >> 6;
    const int lane = tid & 63;
    const int g    = lane >> 4;    // lane group 0..3
    const int lc   = lane & 15;    // 0..15

    const int blk = blockIdx.x;
    const int bh  = blk >> 5;                  // head index 0..31
    const int q0  = (blk & 31) * QB + wave * QW;

    const float* Qb = Q  + ((size_t)bh * SLEN + q0) * DH;
    const float* Kb = KV + (size_t)bh * SLEN * DH;

    // ---- Q A-fragments (persistent): row=lc, d = 32h + g*8 + j ----
    // scaled by (1/8)*log2(e) so softmax runs in exp2 domain
    const float qscale = 0.125f * 1.4426950408889634f;
    bf16x8 qa[2];
#pragma unroll
    for (int h = 0; h < 2; ++h) {
        const float* qp = Qb + (size_t)lc * DH + 32 * h + g * 8;
        float4 f0 = *(const float4*)qp;
        float4 f1 = *(const float4*)(qp + 4);
        qa[h][0] = f2bf(f0.x * qscale); qa[h][1] = f2bf(f0.y * qscale);
        qa[h][2] = f2bf(f0.z * qscale); qa[h][3] = f2bf(f0.w * qscale);
        qa[h][4] = f2bf(f1.x * qscale); qa[h][5] = f2bf(f1.y * qscale);
        qa[h][6] = f2bf(f1.z * qscale); qa[h][7] = f2bf(f1.w * qscale);
    }

    f32x4 oacc[4];
#pragma unroll
    for (int t = 0; t < 4; ++t) oacc[t] = (f32x4){0.f, 0.f, 0.f, 0.f};
    float m[4] = { -INFINITY, -INFINITY, -INFINITY, -INFINITY };
    float l[4] = { 0.f, 0.f, 0.f, 0.f };

    const unsigned rowbase = ((unsigned)bh * SLEN + (unsigned)(q0 + g * 4)) * SLEN;

    // staging indices (constant per thread)
    const int sk_row = tid >> 3;          // 0..31  (k within tile)
    const int sk_c   = tid & 7;           // 16B chunk within row
    const int sv_d   = tid & 63;          // 0..63  (dim)
    const int sv_w   = tid >> 6;          // 0..3   (k-octet)

    for (int k0 = 0; k0 < SLEN; k0 += KB) {
        __syncthreads();   // all waves done reading previous tile

        // ---- stage K tile (bf16, swizzled) ----
        {
            const float* src = Kb + (size_t)(k0 + sk_row) * DH + sk_c * 8;
            float4 f0 = *(const float4*)src;
            float4 f1 = *(const float4*)(src + 4);
            bf16x8 v;
            v[0] = f2bf(f0.x); v[1] = f2bf(f0.y);
            v[2] = f2bf(f0.z); v[3] = f2bf(f0.w);
            v[4] = f2bf(f1.x); v[5] = f2bf(f1.y);
            v[6] = f2bf(f1.z); v[7] = f2bf(f1.w);
            s_k[sk_row * 8 + (sk_c ^ (sk_row & 7))] = v;
        }
        // ---- stage V^T tile (bf16, 80B row stride) ----
        {
            bf16x8 v;
#pragma unroll
            for (int j = 0; j < 8; ++j)
                v[j] = f2bf(Kb[(size_t)(k0 + sv_w * 8 + j) * DH + sv_d]);
            s_vt[sv_d * 5 + sv_w] = v;
        }
        __syncthreads();

        // ---- K B-fragments from LDS: col = key = tt*16+lc, d = 32h+g*8+j ----
        bf16x8 kb[2][2];
#pragma unroll
        for (int tt = 0; tt < 2; ++tt)
#pragma unroll
            for (int h = 0; h < 2; ++h)
                kb[tt][h] = s_k[(tt * 16 + lc) * 8 + ((4 * h + g) ^ (lc & 7))];

        // ---- S = (Q*scale) . K^T ----
        f32x4 s0 = (f32x4){0.f, 0.f, 0.f, 0.f};
        f32x4 s1 = (f32x4){0.f, 0.f, 0.f, 0.f};
        s0 = __builtin_amdgcn_mfma_f32_16x16x32_bf16(qa[0], kb[0][0], s0, 0, 0, 0);
        s0 = __builtin_amdgcn_mfma_f32_16x16x32_bf16(qa[1], kb[0][1], s0, 0, 0, 0);
        s1 = __builtin_amdgcn_mfma_f32_16x16x32_bf16(qa[0], kb[1][0], s1, 0, 0, 0);
        s1 = __builtin_amdgcn_mfma_f32_16x16x32_bf16(qa[1], kb[1][1], s1, 0, 0, 0);

        // ---- online softmax (exp2 domain) + dropout ----
#pragma unroll
        for (int i = 0; i < 4; ++i) {
            float a = s0[i], b = s1[i];
            float t = fmaxf(a, b);
            t = fmaxf(t, __shfl_xor(t, 1));
            t = fmaxf(t, __shfl_xor(t, 2));
            t = fmaxf(t, __shfl_xor(t, 4));
            t = fmaxf(t, __shfl_xor(t, 8));
            float mnew = fmaxf(m[i], t);
            float corr = __builtin_amdgcn_exp2f(m[i] - mnew);
            float p0 = __builtin_amdgcn_exp2f(a - mnew);
            float p1 = __builtin_amdgcn_exp2f(b - mnew);
            float rs = p0 + p1;                  // UNMASKED row sum
            rs += __shfl_xor(rs, 1);
            rs += __shfl_xor(rs, 2);
            rs += __shfl_xor(rs, 4);
            rs += __shfl_xor(rs, 8);
            l[i] = l[i] * corr + rs;
            m[i] = mnew;
            oacc[0][i] *= corr; oacc[1][i] *= corr;
            oacc[2][i] *= corr; oacc[3][i] *= corr;

            unsigned fi = rowbase + (unsigned)i * SLEN + (unsigned)(k0 + lc);
            if (!keep(fi))       p0 = 0.f;
            if (!keep(fi + 16u)) p1 = 0.f;
            s_p[wave][g * 4 + i][lc]      = p0;
            s_p[wave][g * 4 + i][lc + 16] = p1;
        }

        // ---- P A-fragment readback: row = lc, k = g*8 + j ----
        const float* pp = &s_p[wave][lc][g * 8];
        float4 pf0 = *(const float4*)pp;
        float4 pf1 = *(const float4*)(pp + 4);
        bf16x8 pa;
        pa[0] = f2bf(pf0.x); pa[1] = f2bf(pf0.y);
        pa[2] = f2bf(pf0.z); pa[3] = f2bf(pf0.w);
        pa[4] = f2bf(pf1.x); pa[5] = f2bf(pf1.y);
        pa[6] = f2bf(pf1.z); pa[7] = f2bf(pf1.w);

        // ---- O += P . V : V^T B-frag from LDS: col = d = t*16+lc, k = g*8+j ----
#pragma unroll
        for (int t = 0; t < 4; ++t) {
            bf16x8 vb = s_vt[(t * 16 + lc) * 5 + g];
            oacc[t] = __builtin_amdgcn_mfma_f32_16x16x32_bf16(pa, vb, oacc[t], 0, 0, 0);
        }
    }

    // ---- epilogue: O row q0+g*4+i, col d = t*16+lc ----
#pragma unroll
    for (int i = 0; i < 4; ++i) {
        float sc = 1.0f / (l[i] * 0.9f);
        float* orow = O + ((size_t)bh * SLEN + (size_t)(q0 + g * 4 + i)) * DH;
        orow[lc]      = oacc[0][i] * sc;
        orow[16 + lc] = oacc[1][i] * sc;
        orow[32 + lc] = oacc[2][i] * sc;
        orow[48 + lc] = oacc[3][i] * sc;
    }
}

extern "C" void kernel_launch(void* const* d_in, const int* in_sizes, int n_in,
                              void* d_out, int out_size, void* d_ws, size_t ws_size,
                              hipStream_t stream) {
    const float* x1 = (const float*)d_in[0];   // queries
    const float* x2 = (const float*)d_in[1];   // keys == values
    float* out = (float*)d_out;
    const int nblocks = BATCH * NHEAD * (SLEN / QB);   // 32 * 32 = 1024
    attn_mfma_kernel<<<dim3(nblocks), dim3(256), 0, stream>>>(x1, x2, out);
}

// Round 5
// 334.885 us; speedup vs baseline: 1.2709x; 1.2709x over previous
//
#include <hip/hip_runtime.h>
#include <hip/hip_bf16.h>
#include <math.h>

#define BATCH 2
#define NHEAD 16
#define SLEN  2048
#define DH    64
#define WAVES 4            // waves per block
#define QW    16           // q rows per wave
#define QB    (WAVES*QW)   // 64 q rows per block
#define KB    64           // keys per k-step
#define PSTRIDE 68         // dwords per P row in LDS (64 + 4 pad)

typedef __attribute__((ext_vector_type(8))) short bf16x8;
typedef __attribute__((ext_vector_type(4))) float f32x4;

// single-instruction rotate: (x:x) >> (32-d) == rotl(x,d)
__device__ __forceinline__ unsigned rotl32(unsigned x, unsigned d) {
    return __builtin_amdgcn_alignbit(x, x, 32u - d);
}

// jax.random.bernoulli(jax.random.key(42)) bits, jax_threefry_partitionable=True:
// counter = (0, i); bits = out0 ^ out1 of threefry2x32 with key (0, 42).
__device__ __forceinline__ unsigned threefry_bits(unsigned i) {
    const unsigned k0 = 0u, k1 = 42u;
    const unsigned ks[3] = { k0, k1, k0 ^ k1 ^ 0x1BD11BDAu };
    unsigned x0 = 0u + ks[0];
    unsigned x1 = i  + ks[1];
#pragma unroll
    for (int g = 0; g < 5; ++g) {
        if ((g & 1) == 0) {
            x0 += x1; x1 = rotl32(x1, 13u); x1 ^= x0;
            x0 += x1; x1 = rotl32(x1, 15u); x1 ^= x0;
            x0 += x1; x1 = rotl32(x1, 26u); x1 ^= x0;
            x0 += x1; x1 = rotl32(x1,  6u); x1 ^= x0;
        } else {
            x0 += x1; x1 = rotl32(x1, 17u); x1 ^= x0;
            x0 += x1; x1 = rotl32(x1, 29u); x1 ^= x0;
            x0 += x1; x1 = rotl32(x1, 16u); x1 ^= x0;
            x0 += x1; x1 = rotl32(x1, 24u); x1 ^= x0;
        }
        x0 += ks[(g + 1) % 3];
        x1 += ks[(g + 2) % 3] + (unsigned)(g + 1);
    }
    return x0 ^ x1;
}

// keep iff uniform(bits) < 0.9f  ⟺  bits < 7549747<<9
__device__ __forceinline__ int keep(unsigned flat) {
    return threefry_bits(flat) < 3865470464u;
}

// standard cast → compiler pairs into v_cvt_pk_bf16_f32 (RNE)
__device__ __forceinline__ short f2bf(float f) {
    __hip_bfloat16 h = __float2bfloat16(f);
    return *reinterpret_cast<short*>(&h);
}

__global__ __launch_bounds__(256)
void attn_mfma_kernel(const float* __restrict__ Q,
                      const float* __restrict__ KV,
                      float* __restrict__ O) {
    // K tile, bf16 [KB][64]: row = 8 16B-chunks, chunk XOR-swizzled by row&7
    __shared__ bf16x8 s_k[KB * 8];                // 8 KB
    // V^T tile, bf16 [DH][stride 9 chunks], chunks 0..7 = 64 k's
    __shared__ bf16x8 s_vt[DH * 9];               // 9 KB
    // per-wave P relayout buffer (fp32, masked probs)
    __shared__ float s_p[WAVES][QW][PSTRIDE];     // 17.4 KB

    const int tid  = threadIdx.x;
    const int wave = tid >> 6;
    const int lane = tid & 63;
    const int g    = lane >> 4;    // lane group 0..3
    const int lc   = lane & 15;    // 0..15

    const int blk = blockIdx.x;
    const int bh  = blk >> 5;                  // head index 0..31
    const int q0  = (blk & 31) * QB + wave * QW;

    const float* Qb = Q  + ((size_t)bh * SLEN + q0) * DH;
    const float* Kb = KV + (size_t)bh * SLEN * DH;

    // ---- Q A-fragments (persistent): row=lc, d = 32h + g*8 + j ----
    // scaled by (1/8)*log2(e) so softmax runs in exp2 domain
    const float qscale = 0.125f * 1.4426950408889634f;
    bf16x8 qa[2];
#pragma unroll
    for (int h = 0; h < 2; ++h) {
        const float* qp = Qb + (size_t)lc * DH + 32 * h + g * 8;
        float4 f0 = *(const float4*)qp;
        float4 f1 = *(const float4*)(qp + 4);
        qa[h][0] = f2bf(f0.x * qscale); qa[h][1] = f2bf(f0.y * qscale);
        qa[h][2] = f2bf(f0.z * qscale); qa[h][3] = f2bf(f0.w * qscale);
        qa[h][4] = f2bf(f1.x * qscale); qa[h][5] = f2bf(f1.y * qscale);
        qa[h][6] = f2bf(f1.z * qscale); qa[h][7] = f2bf(f1.w * qscale);
    }

    f32x4 oacc[4];
#pragma unroll
    for (int t = 0; t < 4; ++t) oacc[t] = (f32x4){0.f, 0.f, 0.f, 0.f};
    float m[4] = { -INFINITY, -INFINITY, -INFINITY, -INFINITY };
    float l[4] = { 0.f, 0.f, 0.f, 0.f };

    const unsigned rowbase = ((unsigned)bh * SLEN + (unsigned)(q0 + g * 4)) * SLEN;
    const unsigned fib = rowbase + (unsigned)lc;

    // staging indices (constant per thread)
    const int kr0 = tid >> 3;            // K row 0..31 (and +32)
    const int kc0 = tid & 7;             // 16B chunk within row
    const int vd  = tid & 63;            // V dim 0..63
    const int vw  = tid >> 6;            // V k-octet 0..3 (and +4)

    for (int k0 = 0; k0 < SLEN; k0 += KB) {
        __syncthreads();   // all waves done reading previous tile

        // ---- stage K tile (bf16, swizzled): 2 chunks per thread ----
#pragma unroll
        for (int rr = 0; rr < 2; ++rr) {
            const int row = kr0 + rr * 32;
            const float* src = Kb + (size_t)(k0 + row) * DH + kc0 * 8;
            float4 f0 = *(const float4*)src;
            float4 f1 = *(const float4*)(src + 4);
            bf16x8 v;
            v[0] = f2bf(f0.x); v[1] = f2bf(f0.y);
            v[2] = f2bf(f0.z); v[3] = f2bf(f0.w);
            v[4] = f2bf(f1.x); v[5] = f2bf(f1.y);
            v[6] = f2bf(f1.z); v[7] = f2bf(f1.w);
            s_k[row * 8 + (kc0 ^ (row & 7))] = v;
        }
        // ---- stage V^T tile (bf16): 2 chunks per thread, coalesced loads ----
#pragma unroll
        for (int rr = 0; rr < 2; ++rr) {
            const int w = vw + rr * 4;
            bf16x8 v;
#pragma unroll
            for (int j = 0; j < 8; ++j)
                v[j] = f2bf(Kb[(size_t)(k0 + w * 8 + j) * DH + vd]);
            s_vt[vd * 9 + w] = v;
        }
        __syncthreads();

        // ---- S = (Q*scale) . K^T : four 16x16 key-tiles ----
        f32x4 s[4];
#pragma unroll
        for (int tt = 0; tt < 4; ++tt) {
            bf16x8 kb0 = s_k[(tt * 16 + lc) * 8 + (g       ^ (lc & 7))];
            bf16x8 kb1 = s_k[(tt * 16 + lc) * 8 + ((4 + g) ^ (lc & 7))];
            f32x4 acc = (f32x4){0.f, 0.f, 0.f, 0.f};
            acc = __builtin_amdgcn_mfma_f32_16x16x32_bf16(qa[0], kb0, acc, 0, 0, 0);
            s[tt] = __builtin_amdgcn_mfma_f32_16x16x32_bf16(qa[1], kb1, acc, 0, 0, 0);
        }

        // ---- online softmax (exp2 domain) + dropout, per C-reg i ----
#pragma unroll
        for (int i = 0; i < 4; ++i) {
            float a = s[0][i], b = s[1][i], c = s[2][i], d = s[3][i];
            float t = fmaxf(fmaxf(a, b), fmaxf(c, d));
            t = fmaxf(t, __shfl_xor(t, 1));
            t = fmaxf(t, __shfl_xor(t, 2));
            t = fmaxf(t, __shfl_xor(t, 4));
            t = fmaxf(t, __shfl_xor(t, 8));
            if (t > m[i]) {            // exact skip: corr==1 when no new max
                float corr = __builtin_amdgcn_exp2f(m[i] - t);
                l[i] *= corr;
                oacc[0][i] *= corr; oacc[1][i] *= corr;
                oacc[2][i] *= corr; oacc[3][i] *= corr;
                m[i] = t;
            }
            float p0 = __builtin_amdgcn_exp2f(a - m[i]);
            float p1 = __builtin_amdgcn_exp2f(b - m[i]);
            float p2 = __builtin_amdgcn_exp2f(c - m[i]);
            float p3 = __builtin_amdgcn_exp2f(d - m[i]);
            float rs = (p0 + p1) + (p2 + p3);    // UNMASKED row sum
            rs += __shfl_xor(rs, 1);
            rs += __shfl_xor(rs, 2);
            rs += __shfl_xor(rs, 4);
            rs += __shfl_xor(rs, 8);
            l[i] += rs;

            const unsigned fi = fib + (unsigned)i * SLEN + (unsigned)k0;
            if (!keep(fi))       p0 = 0.f;
            if (!keep(fi + 16u)) p1 = 0.f;
            if (!keep(fi + 32u)) p2 = 0.f;
            if (!keep(fi + 48u)) p3 = 0.f;
            float* pr = &s_p[wave][g * 4 + i][0];
            pr[lc]      = p0;
            pr[lc + 16] = p1;
            pr[lc + 32] = p2;
            pr[lc + 48] = p3;
        }

        // ---- P A-fragments: row = lc, k-halves [g*8..] and [32+g*8..] ----
        const float* pp = &s_p[wave][lc][0];
        float4 pf0 = *(const float4*)(pp + g * 8);
        float4 pf1 = *(const float4*)(pp + g * 8 + 4);
        float4 pf2 = *(const float4*)(pp + 32 + g * 8);
        float4 pf3 = *(const float4*)(pp + 32 + g * 8 + 4);
        bf16x8 pa0, pa1;
        pa0[0] = f2bf(pf0.x); pa0[1] = f2bf(pf0.y);
        pa0[2] = f2bf(pf0.z); pa0[3] = f2bf(pf0.w);
        pa0[4] = f2bf(pf1.x); pa0[5] = f2bf(pf1.y);
        pa0[6] = f2bf(pf1.z); pa0[7] = f2bf(pf1.w);
        pa1[0] = f2bf(pf2.x); pa1[1] = f2bf(pf2.y);
        pa1[2] = f2bf(pf2.z); pa1[3] = f2bf(pf2.w);
        pa1[4] = f2bf(pf3.x); pa1[5] = f2bf(pf3.y);
        pa1[6] = f2bf(pf3.z); pa1[7] = f2bf(pf3.w);

        // ---- O += P . V over both k-halves ----
#pragma unroll
        for (int t = 0; t < 4; ++t) {
            bf16x8 vb0 = s_vt[(t * 16 + lc) * 9 + g];
            bf16x8 vb1 = s_vt[(t * 16 + lc) * 9 + 4 + g];
            oacc[t] = __builtin_amdgcn_mfma_f32_16x16x32_bf16(pa0, vb0, oacc[t], 0, 0, 0);
            oacc[t] = __builtin_amdgcn_mfma_f32_16x16x32_bf16(pa1, vb1, oacc[t], 0, 0, 0);
        }
    }

    // ---- epilogue: O row q0+g*4+i, col d = t*16+lc ----
#pragma unroll
    for (int i = 0; i < 4; ++i) {
        float sc = 1.0f / (l[i] * 0.9f);
        float* orow = O + ((size_t)bh * SLEN + (size_t)(q0 + g * 4 + i)) * DH;
        orow[lc]      = oacc[0][i] * sc;
        orow[16 + lc] = oacc[1][i] * sc;
        orow[32 + lc] = oacc[2][i] * sc;
        orow[48 + lc] = oacc[3][i] * sc;
    }
}

extern "C" void kernel_launch(void* const* d_in, const int* in_sizes, int n_in,
                              void* d_out, int out_size, void* d_ws, size_t ws_size,
                              hipStream_t stream) {
    const float* x1 = (const float*)d_in[0];   // queries
    const float* x2 = (const float*)d_in[1];   // keys == values
    float* out = (float*)d_out;
    const int nblocks = BATCH * NHEAD * (SLEN / QB);   // 32 * 32 = 1024
    attn_mfma_kernel<<<dim3(nblocks), dim3(256), 0, stream>>>(x1, x2, out);
}